// Round 2
// baseline (264.748 us; speedup 1.0000x reference)
//
#include <hip/hip_runtime.h>

#define WS 128
#define HW (1024 * 1024)
#define PLANE 8388608   // C * WS * WS = 512 * 16384

typedef _Float16 half4 __attribute__((ext_vector_type(4)));
typedef float floatx4 __attribute__((ext_vector_type(4)));

// H^T-chained MFMA formulation:
//   C1 = W1^T (16x16, K-padded from 7) @ feats^T (16x16)   -> C layout == next B layout
//   C2 = W2^T @ relu(C1 + b1)
//   logit = W3 . relu(C2 + b2) + b3   (VALU partial + shfl_xor reduce over quads)
__global__ __launch_bounds__(256) void instanseg_mfma(
    const float* __restrict__ x,        // (6, 1024, 1024)
    const float* __restrict__ sigma,    // (1, 1024, 1024)
    const float* __restrict__ c,        // (512, 6)
    const float* __restrict__ W1,       // (7, 16)
    const float* __restrict__ b1,       // (16)
    const float* __restrict__ W2,       // (16, 16)
    const float* __restrict__ b2,       // (16)
    const float* __restrict__ W3,       // (16, 1)
    const float* __restrict__ b3,       // (1)
    const int*   __restrict__ cent,     // (512, 2)
    float* __restrict__ out)
{
    const int cid  = blockIdx.y;
    const int lane = threadIdx.x & 63;
    const int wave = threadIdx.x >> 6;
    const int quad = lane >> 4;
    const int sub  = lane & 15;

    const int cy = min(max(cent[2 * cid], 64), 960);
    const int cx = min(max(cent[2 * cid + 1], 64), 960);
    const int cy0 = cy - 64, cx0 = cx - 64;

    // Per-wave fragment setup. A-operand layout: A[m=lane&15][k=4*quad+i].
    // A = W^T, so m = output feature j, k = input feature e: a[i] = W[e][j].
    half4 a1, a2;
    float w3f[4], bb1[4], bb2[4], cc[4];
#pragma unroll
    for (int i = 0; i < 4; ++i) {
        const int e = 4 * quad + i;
        a1[i] = (_Float16)((e < 7) ? W1[e * 16 + sub] : 0.0f);  // K-pad 7->16
        a2[i] = (_Float16)W2[e * 16 + sub];
        w3f[i] = W3[e];
        bb1[i] = b1[e];
        bb2[i] = b2[e];
        cc[i]  = (e < 6) ? c[cid * 6 + e] : 0.0f;
    }
    const float b3v = b3[0];

    const int wavestart = blockIdx.x * 2048 + wave * 512;

    for (int it = 0; it < 8; ++it) {
        const int start = wavestart + it * 64;
        float logit[4];
#pragma unroll
        for (int ch = 0; ch < 4; ++ch) {
            // this chain's 16 pixels: lane sub -> pixel (start + 16*ch + sub)
            const int gp  = start + ch * 16 + sub;
            const int src = (cy0 + (gp >> 7)) * 1024 + cx0 + (gp & 127);

            // B-operand: B[k=4*quad+i][n=sub] = feats^T (channel k, pixel n)
            half4 b0;
#pragma unroll
            for (int i = 0; i < 4; ++i) {
                const int e = 4 * quad + i;
                float v = 0.0f;
                if (e < 6)       v = x[e * HW + src] - cc[i];
                else if (e == 6) v = sigma[src];
                b0[i] = (_Float16)v;
            }

            const floatx4 zero = {0.0f, 0.0f, 0.0f, 0.0f};
            floatx4 c1 = __builtin_amdgcn_mfma_f32_16x16x16f16(a1, b0, zero, 0, 0, 0);

            half4 bh;
#pragma unroll
            for (int i = 0; i < 4; ++i)
                bh[i] = (_Float16)fmaxf(c1[i] + bb1[i], 0.0f);

            floatx4 c2 = __builtin_amdgcn_mfma_f32_16x16x16f16(a2, bh, zero, 0, 0, 0);

            // layer 3: per-lane partial over its 4 k's, then butterfly over quads
            float part = 0.0f;
#pragma unroll
            for (int i = 0; i < 4; ++i)
                part = fmaf(w3f[i], fmaxf(c2[i] + bb2[i], 0.0f), part);
            part += __shfl_xor(part, 16, 64);
            part += __shfl_xor(part, 32, 64);
            logit[ch] = part;
        }

        // lane L stores pixel (start + L), which belongs to chain (L>>4)
        const float l01 = (quad & 1) ? logit[1] : logit[0];
        const float l23 = (quad & 1) ? logit[3] : logit[2];
        const float lg  = (quad & 2) ? l23 : l01;
        const float prob = 1.0f / (1.0f + __expf(-(lg + b3v)));

        const int gps = start + lane;
        const int n   = cid * 16384 + gps;
        out[n]             = prob;
        out[PLANE + n]     = (float)cid;
        out[2 * PLANE + n] = (float)(cy0 + (gps >> 7));
        out[3 * PLANE + n] = (float)(cx0 + (gps & 127));
    }
}

extern "C" void kernel_launch(void* const* d_in, const int* in_sizes, int n_in,
                              void* d_out, int out_size, void* d_ws, size_t ws_size,
                              hipStream_t stream) {
    const float* x     = (const float*)d_in[0];
    const float* sigma = (const float*)d_in[1];
    const float* c     = (const float*)d_in[2];
    const float* W1    = (const float*)d_in[3];
    const float* b1    = (const float*)d_in[4];
    const float* W2    = (const float*)d_in[5];
    const float* b2    = (const float*)d_in[6];
    const float* W3    = (const float*)d_in[7];
    const float* b3    = (const float*)d_in[8];
    const int*   cent  = (const int*)d_in[9];
    float* out = (float*)d_out;

    dim3 grid(8, 512);   // 8 chunks x 512 centroids; 2048 px/block, 512 px/wave
    dim3 block(256);
    instanseg_mfma<<<grid, block, 0, stream>>>(
        x, sigma, c, W1, b1, W2, b2, W3, b3, cent, out);
}

// Round 3
// 208.459 us; speedup vs baseline: 1.2700x; 1.2700x over previous
//
#include <hip/hip_runtime.h>

#define WS 128
#define HW (1024 * 1024)
#define PLANE 8388608   // C * WS * WS = 512 * 16384

typedef _Float16 half4 __attribute__((ext_vector_type(4)));
typedef _Float16 half8 __attribute__((ext_vector_type(8)));
typedef float floatx4 __attribute__((ext_vector_type(4)));

// Kernel A: P[src][j] = sum_e W1[e][j] * xs[e][src]   (window-independent layer-1)
// Stored px-major fp16: P + src*16 + j, so kernel B's B-fragment load is one half4.
__global__ __launch_bounds__(256) void precompute_P(
    const float* __restrict__ x,      // (6, 1024, 1024)
    const float* __restrict__ sigma,  // (1, 1024, 1024)
    const float* __restrict__ W1,     // (7, 16)
    _Float16* __restrict__ P)         // (1024*1024, 16)
{
    const int px = blockIdx.x * 256 + threadIdx.x;
    float g[7];
#pragma unroll
    for (int e = 0; e < 6; ++e) g[e] = x[e * HW + px];
    g[6] = sigma[px];

    half8 lo, hi;
#pragma unroll
    for (int j = 0; j < 16; ++j) {
        float a = 0.0f;
#pragma unroll
        for (int e = 0; e < 7; ++e)
            a = fmaf(g[e], W1[e * 16 + j], a);
        if (j < 8) lo[j] = (_Float16)a; else hi[j - 8] = (_Float16)a;
    }
    *(half8*)(P + (size_t)px * 16)     = lo;
    *(half8*)(P + (size_t)px * 16 + 8) = hi;
}

// Kernel B: per window-pixel  h1 = relu(P[src] - q[cid]);  h2 = relu(W2^T h1 + b2);
//           prob = sigmoid(W3 . h2 + b3).  Layer 2 on the matrix pipe:
//           C = W2^T (A-frag) @ h1^T (B-frag), C layout feeds the VALU epilogue.
__global__ __launch_bounds__(256) void instanseg_mlp(
    const _Float16* __restrict__ P,   // (1024*1024, 16)
    const float* __restrict__ c,      // (512, 6)
    const float* __restrict__ W1,     // (7, 16)
    const float* __restrict__ b1,     // (16)
    const float* __restrict__ W2,     // (16, 16)
    const float* __restrict__ b2,     // (16)
    const float* __restrict__ W3,     // (16, 1)
    const float* __restrict__ b3,     // (1)
    const int*   __restrict__ cent,   // (512, 2)
    float* __restrict__ out)
{
    const int cid  = blockIdx.y;
    const int lane = threadIdx.x & 63;
    const int wave = threadIdx.x >> 6;
    const int quad = lane >> 4;
    const int sub  = lane & 15;

    const int cy = min(max(cent[2 * cid], 64), 960);
    const int cx = min(max(cent[2 * cid + 1], 64), 960);
    const int cy0 = cy - 64, cx0 = cx - 64;

    // A-fragment for layer 2: A[m=sub][k=4*quad+i] = W2[k][m]
    half4 a2;
    float w3f[4], bb2[4];
    half4 qh;   // q[k] = sum_{e<6} W1[e][k]*c[cid][e] - b1[k], k = 4*quad+i
#pragma unroll
    for (int i = 0; i < 4; ++i) {
        const int k = 4 * quad + i;
        a2[i]  = (_Float16)W2[k * 16 + sub];
        w3f[i] = W3[k];
        bb2[i] = b2[k];
        float qv = -b1[k];
#pragma unroll
        for (int e = 0; e < 6; ++e)
            qv = fmaf(W1[e * 16 + k], c[cid * 6 + e], qv);
        qh[i] = (_Float16)qv;
    }
    const float b3v = b3[0];
    const floatx4 zero = {0.0f, 0.0f, 0.0f, 0.0f};

    const int wavestart = blockIdx.x * 2048 + wave * 512;

    for (int it = 0; it < 8; ++it) {
        const int start = wavestart + it * 64;
        float logit[4];
#pragma unroll
        for (int ch = 0; ch < 4; ++ch) {
            const int gp  = start + ch * 16 + sub;
            const int src = (cy0 + (gp >> 7)) * 1024 + cx0 + (gp & 127);

            // B-fragment: channels 4q..4q+3 of pixel sub — one contiguous 8B load
            half4 v = *(const half4*)(P + (size_t)src * 16 + quad * 4);
            half4 h = v - qh;                       // v_pk_add_f16
#pragma unroll
            for (int i = 0; i < 4; ++i)             // relu -> v_pk_max_f16
                h[i] = h[i] > (_Float16)0.0f ? h[i] : (_Float16)0.0f;

            floatx4 c2 = __builtin_amdgcn_mfma_f32_16x16x16f16(a2, h, zero, 0, 0, 0);

            float part = 0.0f;
#pragma unroll
            for (int i = 0; i < 4; ++i)
                part = fmaf(w3f[i], fmaxf(c2[i] + bb2[i], 0.0f), part);
            part += __shfl_xor(part, 16, 64);
            part += __shfl_xor(part, 32, 64);
            logit[ch] = part;
        }

        const float l01 = (quad & 1) ? logit[1] : logit[0];
        const float l23 = (quad & 1) ? logit[3] : logit[2];
        const float lg  = (quad & 2) ? l23 : l01;
        const float prob = 1.0f / (1.0f + __expf(-(lg + b3v)));

        const int gps = start + lane;
        const int n   = cid * 16384 + gps;
        out[n]             = prob;
        out[PLANE + n]     = (float)cid;
        out[2 * PLANE + n] = (float)(cy0 + (gps >> 7));
        out[3 * PLANE + n] = (float)(cx0 + (gps & 127));
    }
}

extern "C" void kernel_launch(void* const* d_in, const int* in_sizes, int n_in,
                              void* d_out, int out_size, void* d_ws, size_t ws_size,
                              hipStream_t stream) {
    const float* x     = (const float*)d_in[0];
    const float* sigma = (const float*)d_in[1];
    const float* c     = (const float*)d_in[2];
    const float* W1    = (const float*)d_in[3];
    const float* b1    = (const float*)d_in[4];
    const float* W2    = (const float*)d_in[5];
    const float* b2    = (const float*)d_in[6];
    const float* W3    = (const float*)d_in[7];
    const float* b3    = (const float*)d_in[8];
    const int*   cent  = (const int*)d_in[9];
    float* out = (float*)d_out;
    _Float16* P = (_Float16*)d_ws;   // 1024*1024*16 fp16 = 32 MB scratch

    precompute_P<<<dim3(HW / 256), dim3(256), 0, stream>>>(x, sigma, W1, P);
    instanseg_mlp<<<dim3(8, 512), dim3(256), 0, stream>>>(
        P, c, W1, b1, W2, b2, W3, b3, cent, out);
}